// Round 2
// baseline (203.459 us; speedup 1.0000x reference)
//
#include <hip/hip_runtime.h>
#include <stdint.h>

// Problem constants (reference setup_inputs: N=4096, D=256, C=1000)
#define NR 4096
#define DD 256
#define NC_TOT 4096000
#define TILES 32
#define NTRI 528
#define NBLK_GRAM (3 * NTRI)
#define PREP_BLKS 6144
#define MSE_BLKS 2048

typedef __bf16 bf16x8 __attribute__((ext_vector_type(8)));
typedef float f32x4 __attribute__((ext_vector_type(4)));
typedef float f32x16 __attribute__((ext_vector_type(16)));
typedef unsigned short u16;

// ws layout:
//   [0,16)                     u32 gram-completion counter (memset 0 each call)
//   [256,  +2048*4)            mse per-block partials
//   [16384, +1584*4)           gram per-block partials
//   [32768, +6*4096*4)         fp32 row sq-norms (6 matrices)
//   [131072, +6*4096*256*2)    bf16 feature data
#define WS_CNT_OFF   0
#define WS_MSEP_OFF  256
#define WS_FEATP_OFF 16384
#define WS_SQN_OFF   32768
#define WS_BF16_OFF  131072

__device__ __forceinline__ u16 f2bf(float x) {
    uint32_t u = __float_as_uint(x);
    u += 0x7FFFu + ((u >> 16) & 1u);   // RNE
    return (u16)(u >> 16);
}

// XOR swizzle: logical (row r, 16B-granule g of 4) -> u16 offset in an 8 KB tile.
// line = 128 B (2 rows); phys granule = pos ^ (line & 7). Spreads any
// 16-lane fragment-read phase across all 32 banks (2/bank = free).
__device__ __forceinline__ int swo(int r, int g) {
    int line = r >> 1;
    int pos = ((r & 1) << 2) | g;
    return line * 64 + ((pos ^ (line & 7)) << 3);
}

// ---------------- prep (fp32->bf16 + row norms) fused with label-MSE ------
__global__ __launch_bounds__(256) void prep_mse_kernel(
    const float* __restrict__ m0, const float* __restrict__ m1,
    const float* __restrict__ m2, const float* __restrict__ m3,
    const float* __restrict__ m4, const float* __restrict__ m5,
    const float4* __restrict__ pred, const float4* __restrict__ target,
    u16* __restrict__ bf, float* __restrict__ sqn, float* __restrict__ msep)
{
    __shared__ float sr[4];
    const int t = threadIdx.x, w = t >> 6, lane = t & 63;
    if (blockIdx.x < PREP_BLKS) {
        const float* mats[6] = {m0, m1, m2, m3, m4, m5};
        int row_id = blockIdx.x * 4 + w;        // 6*4096 rows
        int m = row_id >> 12;                   // wave-uniform
        int r = row_id & 4095;
        const float4* src = (const float4*)(mats[m] + (size_t)r * DD);
        u16* dst = bf + ((size_t)m * NR + r) * DD;
        float4 v = src[lane];
        float ss = v.x * v.x + v.y * v.y + v.z * v.z + v.w * v.w;
        ushort4 o;
        o.x = f2bf(v.x); o.y = f2bf(v.y); o.z = f2bf(v.z); o.w = f2bf(v.w);
        ((ushort4*)dst)[lane] = o;
        #pragma unroll
        for (int off = 32; off; off >>= 1) ss += __shfl_down(ss, off);
        if (lane == 0) sqn[(size_t)m * NR + r] = ss;
    } else {
        const int b2 = blockIdx.x - PREP_BLKS;
        float s = 0.f;
        for (int i = b2 * 256 + t; i < NC_TOT / 4; i += MSE_BLKS * 256) {
            float4 x = pred[i], y = target[i];
            float dx = x.x - y.x, dy = x.y - y.y, dz = x.z - y.z, dw = x.w - y.w;
            s += dx * dx + dy * dy + dz * dz + dw * dw;
        }
        #pragma unroll
        for (int off = 32; off; off >>= 1) s += __shfl_down(s, off);
        if (lane == 0) sr[w] = s;
        __syncthreads();
        if (t == 0) msep[b2] = sr[0] + sr[1] + sr[2] + sr[3];
    }
}

// ---------------- epilogue body, diagonal handling templated --------------
template <bool DIAG>
__device__ __forceinline__ float epilogue(
    const f32x16 accp[2][2], const f32x16 acct[2][2],
    const float s_sqn[4][128], int wm, int wn, int l32, int half)
{
    float local = 0.f;
    #pragma unroll
    for (int mi = 0; mi < 2; mi++) {
        f32x4 sip[4], sit[4];
        #pragma unroll
        for (int rg = 0; rg < 4; rg++) {
            int ib = wm * 64 + mi * 32 + rg * 8 + half * 4;
            sip[rg] = *(const f32x4*)&s_sqn[0][ib];
            sit[rg] = *(const f32x4*)&s_sqn[2][ib];
        }
        #pragma unroll
        for (int ni = 0; ni < 2; ni++) {
            const int j_loc = wn * 64 + ni * 32 + l32;
            const float spj = s_sqn[1][j_loc], stj = s_sqn[3][j_loc];
            const f32x16 gp = accp[mi][ni], gt = acct[mi][ni];
            #pragma unroll
            for (int rg = 0; rg < 4; rg++)
                #pragma unroll
                for (int rr = 0; rr < 4; rr++) {
                    const int q = rg * 4 + rr;
                    float dp2 = fmaf(-2.f, gp[q], sip[rg][rr] + spj);
                    float dt2 = fmaf(-2.f, gt[q], sit[rg][rr] + stj);
                    float dp = __builtin_amdgcn_sqrtf(fmaxf(dp2, 0.f));
                    float dt = __builtin_amdgcn_sqrtf(fmaxf(dt2, 0.f));
                    if (DIAG) {
                        int i_loc = wm * 64 + mi * 32 + rg * 8 + half * 4 + rr;
                        if (i_loc == j_loc) { dp = 0.f; dt = 0.f; }
                    }
                    float d = dp - dt;
                    local = fmaf(d, d, local);
                }
        }
    }
    return local;
}

// ---------------- fused Gram + pairwise-L2 + MSE, triangular tiles --------
__global__ __launch_bounds__(256) void gram_loss_kernel(
    const u16* __restrict__ bf, const float* __restrict__ sqn,
    float* __restrict__ featp, const float* __restrict__ msep,
    unsigned* __restrict__ cnt, float* __restrict__ out)
{
    __shared__ u16 tile[4][4096];     // Ap,Bp,At,Bt 8 KB each, XOR-swizzled
    __shared__ float s_sqn[4][128];
    __shared__ float s_red[8];
    __shared__ int s_last;

    const int f = blockIdx.y;
    int ti = 0, rem = blockIdx.x;
    while (rem >= TILES - ti) { rem -= TILES - ti; ti++; }
    const int tj = ti + rem;

    const int t = threadIdx.x;
    const int w = t >> 6, lane = t & 63;
    const int wm = w >> 1, wn = w & 1;       // 2x2 waves, 64x64 each
    const int l32 = lane & 31, half = lane >> 5;

    const u16* matp = bf + (size_t)f * (NR * DD);
    const u16* matt = bf + (size_t)(3 + f) * (NR * DD);
    const float* sqp = sqn + (size_t)f * NR;
    const float* sqt = sqn + (size_t)(3 + f) * NR;

    for (int i = t; i < 512; i += 256) {
        int which = i >> 7, r = i & 127;
        const float* sp = (which < 2) ? sqp : sqt;
        int trow = (which & 1) ? tj : ti;
        s_sqn[which][r] = sp[trow * 128 + r];
    }

    // inverse swizzle for staging: lane's fixed LDS slot -> (row, granule)
    int rS[2], gS[2];
    #pragma unroll
    for (int p = 0; p < 2; p++) {
        int slot = p * 256 + w * 64 + lane;
        int line = slot >> 3, phys = slot & 7;
        int pos = phys ^ (line & 7);
        rS[p] = (line << 1) | (pos >> 2);
        gS[p] = pos & 3;
    }

    const u16* srcmat[4] = {matp, matp, matt, matt};
    const int srow[4] = {ti * 128, tj * 128, ti * 128, tj * 128};

    f32x16 accp[2][2], acct[2][2];
    #pragma unroll
    for (int a = 0; a < 2; a++)
        #pragma unroll
        for (int b = 0; b < 2; b++) {
            accp[a][b] = (f32x16)(0.f);
            acct[a][b] = (f32x16)(0.f);
        }

    const int rowA0 = wm * 64 + l32, rowA1 = rowA0 + 32;
    const int rowB0 = wn * 64 + l32, rowB1 = rowB0 + 32;

    for (int kc = 0; kc < DD / 32; kc++) {
        #pragma unroll
        for (int m = 0; m < 4; m++)
            #pragma unroll
            for (int p = 0; p < 2; p++) {
                const char* gp = (const char*)srcmat[m] +
                    (size_t)(srow[m] + rS[p]) * (DD * 2) + kc * 64 + gS[p] * 16;
                char* lp = (char*)&tile[m][0] + p * 4096 + w * 1024;
                __builtin_amdgcn_global_load_lds(
                    (const __attribute__((address_space(1))) void*)gp,
                    (__attribute__((address_space(3))) void*)lp, 16, 0, 0);
            }
        __syncthreads();

        #pragma unroll
        for (int s = 0; s < 2; s++) {
            const int g = s * 2 + half;
            bf16x8 aP0 = *(const bf16x8*)&tile[0][swo(rowA0, g)];
            bf16x8 aP1 = *(const bf16x8*)&tile[0][swo(rowA1, g)];
            bf16x8 bP0 = *(const bf16x8*)&tile[1][swo(rowB0, g)];
            bf16x8 bP1 = *(const bf16x8*)&tile[1][swo(rowB1, g)];
            accp[0][0] = __builtin_amdgcn_mfma_f32_32x32x16_bf16(aP0, bP0, accp[0][0], 0, 0, 0);
            accp[0][1] = __builtin_amdgcn_mfma_f32_32x32x16_bf16(aP0, bP1, accp[0][1], 0, 0, 0);
            accp[1][0] = __builtin_amdgcn_mfma_f32_32x32x16_bf16(aP1, bP0, accp[1][0], 0, 0, 0);
            accp[1][1] = __builtin_amdgcn_mfma_f32_32x32x16_bf16(aP1, bP1, accp[1][1], 0, 0, 0);
            bf16x8 aT0 = *(const bf16x8*)&tile[2][swo(rowA0, g)];
            bf16x8 aT1 = *(const bf16x8*)&tile[2][swo(rowA1, g)];
            bf16x8 bT0 = *(const bf16x8*)&tile[3][swo(rowB0, g)];
            bf16x8 bT1 = *(const bf16x8*)&tile[3][swo(rowB1, g)];
            acct[0][0] = __builtin_amdgcn_mfma_f32_32x32x16_bf16(aT0, bT0, acct[0][0], 0, 0, 0);
            acct[0][1] = __builtin_amdgcn_mfma_f32_32x32x16_bf16(aT0, bT1, acct[0][1], 0, 0, 0);
            acct[1][0] = __builtin_amdgcn_mfma_f32_32x32x16_bf16(aT1, bT0, acct[1][0], 0, 0, 0);
            acct[1][1] = __builtin_amdgcn_mfma_f32_32x32x16_bf16(aT1, bT1, acct[1][1], 0, 0, 0);
        }
        __syncthreads();
    }

    float local = (ti == tj)
        ? epilogue<true >(accp, acct, s_sqn, wm, wn, l32, half)
        : epilogue<false>(accp, acct, s_sqn, wm, wn, l32, half);

    #pragma unroll
    for (int off = 32; off; off >>= 1) local += __shfl_down(local, off);
    if (lane == 0) s_red[w] = local;
    __syncthreads();
    if (t == 0) {
        float bs = s_red[0] + s_red[1] + s_red[2] + s_red[3];
        featp[f * NTRI + blockIdx.x] = (ti == tj) ? bs : 2.f * bs;
        __threadfence();
        unsigned old = atomicAdd(cnt, 1u);
        s_last = (old == NBLK_GRAM - 1) ? 1 : 0;
    }
    __syncthreads();

    if (s_last) {                       // last block: global combine
        __threadfence();
        float s = 0.f, m = 0.f;
        for (int i = t; i < NBLK_GRAM; i += 256) s += featp[i];
        for (int i = t; i < MSE_BLKS; i += 256) m += msep[i];
        #pragma unroll
        for (int off = 32; off; off >>= 1) {
            s += __shfl_down(s, off);
            m += __shfl_down(m, off);
        }
        if (lane == 0) { s_red[w] = s; s_red[4 + w] = m; }
        __syncthreads();
        if (t == 0) {
            float fs = s_red[0] + s_red[1] + s_red[2] + s_red[3];
            float ms = s_red[4] + s_red[5] + s_red[6] + s_red[7];
            out[0] = 0.2f * (ms / (float)NC_TOT) +
                     (0.8f / 3.0f) * (fs / ((float)NR * (float)NR));
        }
    }
}

extern "C" void kernel_launch(void* const* d_in, const int* in_sizes, int n_in,
                              void* d_out, int out_size, void* d_ws, size_t ws_size,
                              hipStream_t stream) {
    unsigned* cnt  = (unsigned*)d_ws;
    float* msep    = (float*)((char*)d_ws + WS_MSEP_OFF);
    float* featp   = (float*)((char*)d_ws + WS_FEATP_OFF);
    float* sqn     = (float*)((char*)d_ws + WS_SQN_OFF);
    u16* bf        = (u16*)((char*)d_ws + WS_BF16_OFF);

    hipMemsetAsync(d_ws, 0, 16, stream);   // zero completion counter

    prep_mse_kernel<<<PREP_BLKS + MSE_BLKS, 256, 0, stream>>>(
        (const float*)d_in[2], (const float*)d_in[3], (const float*)d_in[4],
        (const float*)d_in[5], (const float*)d_in[6], (const float*)d_in[7],
        (const float4*)d_in[0], (const float4*)d_in[1], bf, sqn, msep);

    gram_loss_kernel<<<dim3(NTRI, 3), 256, 0, stream>>>(
        bf, sqn, featp, msep, cnt, (float*)d_out);
}

// Round 3
// 191.350 us; speedup vs baseline: 1.0633x; 1.0633x over previous
//
#include <hip/hip_runtime.h>
#include <stdint.h>

// Problem constants (reference setup_inputs: N=4096, D=256, C=1000)
#define NR 4096
#define DD 256
#define NC_TOT 4096000
#define TILES 32
#define NTRI 528
#define NBLK_GRAM (3 * NTRI)

typedef __bf16 bf16x8 __attribute__((ext_vector_type(8)));
typedef float f32x4 __attribute__((ext_vector_type(4)));
typedef unsigned short u16;

// ws layout:
//   [0,16)                   u32 gram-completion counter (zeroed by prep)
//   [256,  +2048*4)          mse per-block partials
//   [16384, +1584*4)         gram per-block partials
//   [32768, +6*4096*4)       fp32 row sq-norms
//   [131072, +6*4096*256*2)  bf16 feature data
#define WS_MSEP_OFF  256
#define WS_FEATP_OFF 16384
#define WS_SQN_OFF   32768
#define WS_BF16_OFF  131072

__device__ __forceinline__ u16 f2bf(float x) {
    uint32_t u = __float_as_uint(x);
    u += 0x7FFFu + ((u >> 16) & 1u);   // RNE
    return (u16)(u >> 16);
}

// ---------------- prep (fp32->bf16 + row norms) + label-MSE + cnt reset ---
__global__ __launch_bounds__(256) void prep_mse_kernel(
    const float* __restrict__ m0, const float* __restrict__ m1,
    const float* __restrict__ m2, const float* __restrict__ m3,
    const float* __restrict__ m4, const float* __restrict__ m5,
    const float4* __restrict__ pred, const float4* __restrict__ target,
    u16* __restrict__ bf, float* __restrict__ sqn, float* __restrict__ msep,
    unsigned* __restrict__ cnt)
{
    __shared__ float sr[4];
    const int t = threadIdx.x, w = t >> 6, lane = t & 63;
    const int y = blockIdx.y;
    if (y == 0 && blockIdx.x == 0 && t == 0) *cnt = 0u;

    if (y < 6) {
        const float* mp = m0;                       // uniform select, no scratch
        if (y == 1) mp = m1;
        else if (y == 2) mp = m2;
        else if (y == 3) mp = m3;
        else if (y == 4) mp = m4;
        else if (y == 5) mp = m5;
        int r = blockIdx.x * 4 + w;                 // 1024 blocks x 4 rows
        const float4* src = (const float4*)(mp + (size_t)r * DD);
        u16* dst = bf + ((size_t)y * NR + r) * DD;
        float4 v = src[lane];
        float ss = v.x * v.x + v.y * v.y + v.z * v.z + v.w * v.w;
        ushort4 o;
        o.x = f2bf(v.x); o.y = f2bf(v.y); o.z = f2bf(v.z); o.w = f2bf(v.w);
        ((ushort4*)dst)[lane] = o;
        #pragma unroll
        for (int off = 32; off; off >>= 1) ss += __shfl_down(ss, off);
        if (lane == 0) sqn[(size_t)y * NR + r] = ss;
    } else {
        const int b2 = (y - 6) * 1024 + blockIdx.x;   // 2048 mse blocks
        float s = 0.f;
        for (int i = b2 * 256 + t; i < NC_TOT / 4; i += 2048 * 256) {
            float4 x = pred[i], yv = target[i];
            float dx = x.x - yv.x, dy = x.y - yv.y;
            float dz = x.z - yv.z, dw = x.w - yv.w;
            s += dx * dx + dy * dy + dz * dz + dw * dw;
        }
        #pragma unroll
        for (int off = 32; off; off >>= 1) s += __shfl_down(s, off);
        if (lane == 0) sr[w] = s;
        __syncthreads();
        if (t == 0) msep[b2] = sr[0] + sr[1] + sr[2] + sr[3];
    }
}

// ---------------- epilogue, diagonal handling templated -------------------
template <bool DIAG>
__device__ __forceinline__ float epilogue(
    const f32x4 accp[4][4], const f32x4 acct[4][4],
    const float s_sqn[4][128], int wm, int wn, int quad, int l16)
{
    float local = 0.f;
    #pragma unroll
    for (int mi = 0; mi < 4; mi++) {
        const int i0 = wm * 64 + mi * 16 + quad * 4;
        const f32x4 sip = *(const f32x4*)&s_sqn[0][i0];
        const f32x4 sit = *(const f32x4*)&s_sqn[2][i0];
        #pragma unroll
        for (int ni = 0; ni < 4; ni++) {
            const int j_loc = wn * 64 + ni * 16 + l16;
            const float spj = s_sqn[1][j_loc], stj = s_sqn[3][j_loc];
            const f32x4 gp = accp[mi][ni], gt = acct[mi][ni];
            #pragma unroll
            for (int r = 0; r < 4; r++) {
                float dp2 = fmaf(-2.f, gp[r], sip[r] + spj);
                float dt2 = fmaf(-2.f, gt[r], sit[r] + stj);
                float dp = __builtin_amdgcn_sqrtf(fmaxf(dp2, 0.f));
                float dt = __builtin_amdgcn_sqrtf(fmaxf(dt2, 0.f));
                if (DIAG) {
                    if (i0 + r == j_loc) { dp = 0.f; dt = 0.f; }
                }
                float d = dp - dt;
                local = fmaf(d, d, local);
            }
        }
    }
    return local;
}

// ---------------- fused Gram + pairwise-L2 + MSE, triangular tiles --------
// Double-buffered staging, 1 barrier per K-chunk: glds(kc+1) issues before
// the MFMA of kc, so the barrier's vmcnt drain overlaps compute.
__global__ __launch_bounds__(256) void gram_loss_kernel(
    const u16* __restrict__ bf, const float* __restrict__ sqn,
    float* __restrict__ featp, const float* __restrict__ msep,
    unsigned* __restrict__ cnt, float* __restrict__ out)
{
    __shared__ u16 tile[2][4][4096];   // 2 x (Ap,Bp,At,Bt) x 8 KB = 64 KB
    __shared__ float s_sqn[4][128];
    __shared__ float s_red[8];
    __shared__ int s_last;

    const int f = blockIdx.y;
    int ti = 0, rem = blockIdx.x;
    while (rem >= TILES - ti) { rem -= TILES - ti; ti++; }
    const int tj = ti + rem;

    const int t = threadIdx.x;
    const int w = t >> 6, lane = t & 63;
    const int wm = w >> 1, wn = w & 1;        // 2x2 waves, 64x64 each
    const int quad = lane >> 4, l16 = lane & 15;

    const u16* matp = bf + (size_t)f * (NR * DD);
    const u16* matt = bf + (size_t)(3 + f) * (NR * DD);
    const float* sqp = sqn + (size_t)f * NR;
    const float* sqt = sqn + (size_t)(3 + f) * NR;

    for (int i = t; i < 512; i += 256) {
        int which = i >> 7, r = i & 127;
        const float* sp = (which < 2) ? sqp : sqt;
        int trow = (which & 1) ? tj : ti;
        s_sqn[which][r] = sp[trow * 128 + r];
    }

    const u16* srcmat[4] = {matp, matp, matt, matt};
    const int srow[4] = {ti * 128, tj * 128, ti * 128, tj * 128};

    // stage 4 tiles of 128x32 bf16 for K-chunk kc into buffer b
    auto stage = [&](int b, int kc) {
        #pragma unroll
        for (int m = 0; m < 4; m++) {
            const char* gbase = (const char*)srcmat[m] +
                                (size_t)srow[m] * (DD * 2) + kc * 64;
            char* lbase = (char*)&tile[b][m][0] + w * 1024;
            #pragma unroll
            for (int p = 0; p < 2; p++) {
                int o = p * 4096 + t * 16;
                const char* gp = gbase + (size_t)(o >> 6) * (DD * 2) + (o & 63);
                __builtin_amdgcn_global_load_lds(
                    (const __attribute__((address_space(1))) void*)gp,
                    (__attribute__((address_space(3))) void*)(lbase + p * 4096),
                    16, 0, 0);
            }
        }
    };

    f32x4 accp[4][4], acct[4][4];
    #pragma unroll
    for (int a = 0; a < 4; a++)
        #pragma unroll
        for (int bb = 0; bb < 4; bb++) {
            accp[a][bb] = f32x4{0.f, 0.f, 0.f, 0.f};
            acct[a][bb] = f32x4{0.f, 0.f, 0.f, 0.f};
        }

    stage(0, 0);
    __syncthreads();

    for (int kc = 0; kc < DD / 32; kc++) {
        const int b = kc & 1;
        if (kc < DD / 32 - 1) stage(b ^ 1, kc + 1);   // prefetch next chunk

        const u16* tp = &tile[b][0][0];
        const int colo = quad * 8;                     // u16 offset of K-granule
        bf16x8 afr[4], bfr[4];
        #pragma unroll
        for (int mi = 0; mi < 4; mi++)
            afr[mi] = *(const bf16x8*)&tp[0 * 4096 + (wm * 64 + mi * 16 + l16) * 32 + colo];
        #pragma unroll
        for (int ni = 0; ni < 4; ni++)
            bfr[ni] = *(const bf16x8*)&tp[1 * 4096 + (wn * 64 + ni * 16 + l16) * 32 + colo];
        #pragma unroll
        for (int mi = 0; mi < 4; mi++)
            #pragma unroll
            for (int ni = 0; ni < 4; ni++)
                accp[mi][ni] = __builtin_amdgcn_mfma_f32_16x16x32_bf16(
                    afr[mi], bfr[ni], accp[mi][ni], 0, 0, 0);
        #pragma unroll
        for (int mi = 0; mi < 4; mi++)
            afr[mi] = *(const bf16x8*)&tp[2 * 4096 + (wm * 64 + mi * 16 + l16) * 32 + colo];
        #pragma unroll
        for (int ni = 0; ni < 4; ni++)
            bfr[ni] = *(const bf16x8*)&tp[3 * 4096 + (wn * 64 + ni * 16 + l16) * 32 + colo];
        #pragma unroll
        for (int mi = 0; mi < 4; mi++)
            #pragma unroll
            for (int ni = 0; ni < 4; ni++)
                acct[mi][ni] = __builtin_amdgcn_mfma_f32_16x16x32_bf16(
                    afr[mi], bfr[ni], acct[mi][ni], 0, 0, 0);

        __syncthreads();   // drains prefetch vmcnt + readers done (one barrier/iter)
    }

    float local = (ti == tj)
        ? epilogue<true >(accp, acct, s_sqn, wm, wn, quad, l16)
        : epilogue<false>(accp, acct, s_sqn, wm, wn, quad, l16);

    #pragma unroll
    for (int off = 32; off; off >>= 1) local += __shfl_down(local, off);
    if (lane == 0) s_red[w] = local;
    __syncthreads();
    if (t == 0) {
        float bs = s_red[0] + s_red[1] + s_red[2] + s_red[3];
        featp[f * NTRI + blockIdx.x] = (ti == tj) ? bs : 2.f * bs;
        __threadfence();
        unsigned old = atomicAdd(cnt, 1u);
        s_last = (old == NBLK_GRAM - 1) ? 1 : 0;
    }
    __syncthreads();

    if (s_last) {                       // last block: global combine
        __threadfence();
        float s = 0.f, m = 0.f;
        for (int i = t; i < NBLK_GRAM; i += 256) s += featp[i];
        for (int i = t; i < 2048; i += 256) m += msep[i];
        #pragma unroll
        for (int off = 32; off; off >>= 1) {
            s += __shfl_down(s, off);
            m += __shfl_down(m, off);
        }
        if (lane == 0) { s_red[w] = s; s_red[4 + w] = m; }
        __syncthreads();
        if (t == 0) {
            float fs = s_red[0] + s_red[1] + s_red[2] + s_red[3];
            float ms = s_red[4] + s_red[5] + s_red[6] + s_red[7];
            out[0] = 0.2f * (ms / (float)NC_TOT) +
                     (0.8f / 3.0f) * (fs / ((float)NR * (float)NR));
        }
    }
}

extern "C" void kernel_launch(void* const* d_in, const int* in_sizes, int n_in,
                              void* d_out, int out_size, void* d_ws, size_t ws_size,
                              hipStream_t stream) {
    unsigned* cnt  = (unsigned*)d_ws;
    float* msep    = (float*)((char*)d_ws + WS_MSEP_OFF);
    float* featp   = (float*)((char*)d_ws + WS_FEATP_OFF);
    float* sqn     = (float*)((char*)d_ws + WS_SQN_OFF);
    u16* bf        = (u16*)((char*)d_ws + WS_BF16_OFF);

    prep_mse_kernel<<<dim3(1024, 8), 256, 0, stream>>>(
        (const float*)d_in[2], (const float*)d_in[3], (const float*)d_in[4],
        (const float*)d_in[5], (const float*)d_in[6], (const float*)d_in[7],
        (const float4*)d_in[0], (const float4*)d_in[1], bf, sqn, msep, cnt);

    gram_loss_kernel<<<dim3(NTRI, 3), 256, 0, stream>>>(
        bf, sqn, featp, msep, cnt, (float*)d_out);
}